// Round 12
// baseline (207.203 us; speedup 1.0000x reference)
//
#include <hip/hip_runtime.h>
#include <math.h>

// ---------------------------------------------------------------------------
// CausalAttention — round 12.
// r11 post-mortem: single-barrier neutral (202.4 vs 199.4) -> QKV's ~71us is
// load-throughput/structure-bound, not barrier-bound. This round attacks the
// non-GEMM overhead instead:
//   * cvt_x ELIMINATED: gemm_qkv reads x fp32 directly; A-side reg-staged
//     (global float4 x2 -> f2bf pack -> ds_write_b128), B-side GLDS. Mixed
//     vmcnt queue (4 ops/iter: 2 A-loads + 2 B-GLDS): head gate vmcnt(4);
//     pre-A-write gate vmcnt(6) (t<=29) / vmcnt(2) (t==30). K=1024 -> full
//     unroll so ra[t&1]/buf[t%3] are compile-time (no scratch).
//   * softmax: 16B vector loads/stores + write-trim to ((row>>7)+1)<<7 cols
//     (exactly PV's k-clip read region) — ~45% less P write traffic.
// QK/PV/transpose/cvt_wt: unchanged r11 (single-barrier counted-vmcnt GEMM).
// ---------------------------------------------------------------------------

typedef float  f32x4  __attribute__((ext_vector_type(4)));
typedef int    i32x4  __attribute__((ext_vector_type(4)));
typedef __bf16 bf16x8 __attribute__((ext_vector_type(8)));

__device__ inline ushort f2bf(float f) {
    union { float f; unsigned u; } a; a.f = f;
    unsigned u = a.u;
    return (ushort)((u + 0x7fffu + ((u >> 16) & 1u)) >> 16);  // RNE
}
__device__ inline bf16x8 as_bf(i32x4 v) {
    union { i32x4 i; bf16x8 b; } u; u.i = v; return u.b;
}
__device__ inline i32x4 pack8(float4 a, float4 b) {
    i32x4 r;
    r[0] = (int)((unsigned)f2bf(a.x) | ((unsigned)f2bf(a.y) << 16));
    r[1] = (int)((unsigned)f2bf(a.z) | ((unsigned)f2bf(a.w) << 16));
    r[2] = (int)((unsigned)f2bf(b.x) | ((unsigned)f2bf(b.y) << 16));
    r[3] = (int)((unsigned)f2bf(b.z) | ((unsigned)f2bf(b.w) << 16));
    return r;
}

#define GLDS(gp, lp)                                                         \
    __builtin_amdgcn_global_load_lds(                                        \
        (const __attribute__((address_space(1))) void*)(gp),                 \
        (__attribute__((address_space(3))) void*)(lp), 16, 0, 0)

#define BKK 32

// 16B-chunk XOR swizzle within a 64B LDS row (involution; 0 conflicts, r5)
__device__ inline int swz(int row, int c) { return c ^ ((row >> 1) & 3); }

// ================= QKV: A = x fp32 (reg-staged), B = Wt3 (GLDS) =============
__global__ __launch_bounds__(512, 4) void gemm_qkv(
    const float* __restrict__ X,      // [8192][1024] fp32
    const ushort* __restrict__ W,     // [3072][1024] bf16 (pre-transposed)
    ushort* __restrict__ C)           // [8192][3072] bf16
{
    const int m0 = blockIdx.y * 128;
    const int n0 = blockIdx.x * 256;

    __shared__ ushort As[3][128 * BKK];
    __shared__ ushort Bs[3][256 * BKK];

    const int tid = threadIdx.x;
    const int l   = tid & 63;
    const int w   = tid >> 6;             // wave 0..7
    const int g   = l >> 4;
    const int r16 = l & 15;
    const int wr  = w >> 2, wc = w & 3;   // 2M x 4N, wave tile 64x64

    f32x4 acc[4][4];
#pragma unroll
    for (int mi = 0; mi < 4; ++mi)
#pragma unroll
        for (int ni = 0; ni < 4; ++ni)
            acc[mi][ni] = (f32x4){0.f, 0.f, 0.f, 0.f};

    const int srow = w * 16 + (l >> 2);   // A/B staging row 0..127
    const int cg   = swz(srow, l & 3);    // pre-swizzled source chunk
    const float*  gA = X + (size_t)(m0 + srow) * 1024 + cg * 8;
    const ushort* gB = W + (size_t)(n0 + srow) * 1024 + cg * 8;
    const int wslot = srow * BKK + (l & 3) * 8;   // thread's ds_write slot

    float4 ra[2][2];   // A-regs, 2 tiles in flight (full unroll -> registers)

    // prologue: issue A(0),B(0),A(1),B(1); write A(0) once it lands
    ra[0][0] = *(const float4*)(gA + 0);
    ra[0][1] = *(const float4*)(gA + 4);
    GLDS(gB + 0, &Bs[0][(w * 16) * BKK]);
    GLDS(gB + 0 + (size_t)128 * 1024, &Bs[0][(128 + w * 16) * BKK]);
    ra[1][0] = *(const float4*)(gA + BKK);
    ra[1][1] = *(const float4*)(gA + BKK + 4);
    GLDS(gB + BKK, &Bs[1][(w * 16) * BKK]);
    GLDS(gB + BKK + (size_t)128 * 1024, &Bs[1][(128 + w * 16) * BKK]);
    asm volatile("s_waitcnt vmcnt(6)" ::: "memory");   // A(0) landed
    *(i32x4*)&As[0][wslot] = pack8(ra[0][0], ra[0][1]);

#pragma unroll
    for (int t = 0; t < 32; ++t) {
        if (t < 31) asm volatile("s_waitcnt vmcnt(4)" ::: "memory");
        else        asm volatile("s_waitcnt vmcnt(0)" ::: "memory");
        asm volatile("s_waitcnt lgkmcnt(0)" ::: "memory");  // A-write visible
        __builtin_amdgcn_s_barrier();   // tile t in LDS; t-1 reads retired
        asm volatile("" ::: "memory");

        if (t + 2 < 32) {               // issue tile t+2 (A regs + B GLDS)
            ra[t & 1][0] = *(const float4*)(gA + (t + 2) * BKK);
            ra[t & 1][1] = *(const float4*)(gA + (t + 2) * BKK + 4);
            GLDS(gB + (t + 2) * BKK, &Bs[(t + 2) % 3][(w * 16) * BKK]);
            GLDS(gB + (t + 2) * BKK + (size_t)128 * 1024,
                 &Bs[(t + 2) % 3][(128 + w * 16) * BKK]);
        }

        i32x4 av[4], bv[4];
#pragma unroll
        for (int mi = 0; mi < 4; ++mi) {
            const int r = wr * 64 + mi * 16 + r16;
            av[mi] = *(const i32x4*)(&As[t % 3][r * BKK + swz(r, g) * 8]);
        }
#pragma unroll
        for (int ni = 0; ni < 4; ++ni) {
            const int r = wc * 64 + ni * 16 + r16;
            bv[ni] = *(const i32x4*)(&Bs[t % 3][r * BKK + swz(r, g) * 8]);
        }

        __builtin_amdgcn_s_setprio(1);
#pragma unroll
        for (int mi = 0; mi < 4; ++mi)
#pragma unroll
            for (int ni = 0; ni < 4; ++ni)
                acc[mi][ni] = __builtin_amdgcn_mfma_f32_16x16x32_bf16(
                    as_bf(av[mi]), as_bf(bv[ni]), acc[mi][ni], 0, 0, 0);
        __builtin_amdgcn_s_setprio(0);
        asm volatile("" ::: "memory");

        if (t < 31) {                   // stage A(t+1) into its LDS buffer
            if (t <= 29) asm volatile("s_waitcnt vmcnt(6)" ::: "memory");
            else         asm volatile("s_waitcnt vmcnt(2)" ::: "memory");
            *(i32x4*)&As[(t + 1) % 3][wslot] =
                pack8(ra[(t + 1) & 1][0], ra[(t + 1) & 1][1]);
        }
    }

    // epilogue: bf16 C[r][c]; C/D map col=lane&15, row=(lane>>4)*4+reg
#pragma unroll
    for (int mi = 0; mi < 4; ++mi) {
#pragma unroll
        for (int ni = 0; ni < 4; ++ni) {
#pragma unroll
            for (int rr = 0; rr < 4; ++rr) {
                const int gr = m0 + wr * 64 + mi * 16 + g * 4 + rr;
                const int gc = n0 + wc * 64 + ni * 16 + r16;
                C[(size_t)gr * 3072 + gc] = f2bf(acc[mi][ni][rr]);
            }
        }
    }
}

// ================== GEMM (QK + PV) — r11 single-barrier ====================
// MODE 1: causal block-skip (scores)  2: k-clip (PV).  OUT 0: fp32 C*alpha.
template <int BMT, int BNT, int MODE>
__global__ __launch_bounds__((BMT / 64) * (BNT / 64) * 64,
                             ((BMT / 64) * (BNT / 64) == 8) ? 4 : 3)
void gemm_bf16(
    const ushort* __restrict__ A, const ushort* __restrict__ B0,
    float* __restrict__ Cf,
    int N, int K, int lda, int ldb,
    long long sA, long long sB, long long sC, float alpha)
{
    constexpr int NWC = BNT / 64;
    constexpr int T   = (BMT / 64) * NWC * 64;
    constexpr int RPG = T / 4;
    constexpr int IA  = BMT / RPG;
    constexpr int IB  = BNT / RPG;
    constexpr int L   = IA + IB;
    static_assert(L == 3 || L == 4, "gate literals cover L=3,4");

    A  += (long long)blockIdx.z * sA;
    B0 += (long long)blockIdx.z * sB;

    int byi = (int)gridDim.y - 1 - (int)blockIdx.y;   // longest rows first

    const int m0 = byi * BMT;
    const int n0 = blockIdx.x * BNT;
    if (MODE == 1 && n0 > m0 + (BMT - 1)) return;
    int kend = K;
    if (MODE == 2) kend = min(K, m0 + BMT);

    __shared__ ushort As[3][BMT * BKK];
    __shared__ ushort Bs[3][BNT * BKK];

    const int tid = threadIdx.x;
    const int l   = tid & 63;
    const int w   = tid >> 6;
    const int g   = l >> 4;
    const int r16 = l & 15;
    const int wr  = w / NWC, wc = w % NWC;

    f32x4 acc[4][4];
#pragma unroll
    for (int mi = 0; mi < 4; ++mi)
#pragma unroll
        for (int ni = 0; ni < 4; ++ni)
            acc[mi][ni] = (f32x4){0.f, 0.f, 0.f, 0.f};

    const int srow = w * 16 + (l >> 2);
    const int cg   = swz(srow, l & 3);
    const ushort* gA = A  + (size_t)(m0 + srow) * lda + cg * 8;
    const ushort* gB = B0 + (size_t)(n0 + srow) * ldb + cg * 8;

#define STAGE(bi, k0)                                                        \
    do {                                                                     \
        _Pragma("unroll")                                                    \
        for (int ia = 0; ia < IA; ++ia)                                      \
            GLDS(gA + (k0) + (size_t)(ia * RPG) * lda,                       \
                 &As[bi][(ia * RPG + w * 16) * BKK]);                        \
        _Pragma("unroll")                                                    \
        for (int ib = 0; ib < IB; ++ib)                                      \
            GLDS(gB + (k0) + (size_t)(ib * RPG) * ldb,                       \
                 &Bs[bi][(ib * RPG + w * 16) * BKK]);                        \
    } while (0)

    const int nt = kend / BKK;
    STAGE(0, 0);
    if (nt > 1) STAGE(1, BKK);

    int cur = 0;
    for (int t = 0; t < nt; ++t) {
        if (t + 1 < nt) {
            if constexpr (L == 3)
                asm volatile("s_waitcnt vmcnt(3)" ::: "memory");
            else
                asm volatile("s_waitcnt vmcnt(4)" ::: "memory");
        } else {
            asm volatile("s_waitcnt vmcnt(0)" ::: "memory");
        }
        __builtin_amdgcn_s_barrier();
        asm volatile("" ::: "memory");

        const int nxt = (cur >= 1) ? cur - 1 : 2;
        if (t + 2 < nt) STAGE(nxt, (t + 2) * BKK);

        i32x4 av[4], bv[4];
#pragma unroll
        for (int mi = 0; mi < 4; ++mi) {
            const int r = wr * 64 + mi * 16 + r16;
            av[mi] = *(const i32x4*)(&As[cur][r * BKK + swz(r, g) * 8]);
        }
#pragma unroll
        for (int ni = 0; ni < 4; ++ni) {
            const int r = wc * 64 + ni * 16 + r16;
            bv[ni] = *(const i32x4*)(&Bs[cur][r * BKK + swz(r, g) * 8]);
        }

        __builtin_amdgcn_s_setprio(1);
#pragma unroll
        for (int mi = 0; mi < 4; ++mi)
#pragma unroll
            for (int ni = 0; ni < 4; ++ni)
                acc[mi][ni] = __builtin_amdgcn_mfma_f32_16x16x32_bf16(
                    as_bf(av[mi]), as_bf(bv[ni]), acc[mi][ni], 0, 0, 0);
        __builtin_amdgcn_s_setprio(0);

        asm volatile("" ::: "memory");
        cur = (cur == 2) ? 0 : cur + 1;
    }
#undef STAGE

#pragma unroll
    for (int mi = 0; mi < 4; ++mi) {
#pragma unroll
        for (int ni = 0; ni < 4; ++ni) {
#pragma unroll
            for (int rr = 0; rr < 4; ++rr) {
                const int gr = m0 + wr * 64 + mi * 16 + g * 4 + rr;
                const int gc = n0 + wc * 64 + ni * 16 + r16;
                Cf[(long long)blockIdx.z * sC + (size_t)gr * N + gc] =
                    acc[mi][ni][rr] * alpha;
            }
        }
    }
}

// V slice of merged QKV [8192][3072] (cols 2048..3071) -> Vt[b][d][s]
__global__ __launch_bounds__(256) void transpose_v(
    const ushort* __restrict__ QKV, ushort* __restrict__ Vt)
{
    __shared__ ushort t[64][65];
    const int d0 = blockIdx.x * 64;
    const int r0 = blockIdx.y * 64;
    const int tx = threadIdx.x & 31;
    const int ty = threadIdx.x >> 5;

#pragma unroll
    for (int p = 0; p < 8; ++p) {
        const int r = ty + p * 8;
        const ushort2 u = *(const ushort2*)(
            QKV + (size_t)(r0 + r) * 3072 + 2048 + d0 + 2 * tx);
        t[r][2 * tx]     = u.x;
        t[r][2 * tx + 1] = u.y;
    }
    __syncthreads();

    const int b = r0 >> 11, s0 = r0 & 2047;
#pragma unroll
    for (int p = 0; p < 8; ++p) {
        const int d = ty + p * 8;
        ushort2 o;
        o.x = t[2 * tx][d];
        o.y = t[2 * tx + 1][d];
        *(ushort2*)(Vt + (size_t)b * 2097152 + (size_t)(d0 + d) * 2048
                    + s0 + 2 * tx) = o;
    }
}

// fp32 scores -> bf16 P in place; 16B vector IO; write only the first
// ((row>>7)+1)<<7 cols (exactly PV's k-clip read region).
__global__ __launch_bounds__(256) void softmax_bf16(float* __restrict__ Sc)
{
    const int row = blockIdx.x;
    float* base = Sc + ((size_t)blockIdx.y * 2048 + row) * 2048;
    const int tid = threadIdx.x;
    const int j0  = tid * 8;

    const float4 a = *(const float4*)(base + j0);
    const float4 b = *(const float4*)(base + j0 + 4);
    float s[8] = {a.x, a.y, a.z, a.w, b.x, b.y, b.z, b.w};

    __shared__ float red[256];
    float m = -INFINITY;
#pragma unroll
    for (int i = 0; i < 8; ++i) {
        if (j0 + i > row) s[i] = -INFINITY;
        m = fmaxf(m, s[i]);
    }
    red[tid] = m;
    __syncthreads();
    for (int st = 128; st > 0; st >>= 1) {
        if (tid < st) red[tid] = fmaxf(red[tid], red[tid + st]);
        __syncthreads();
    }
    m = red[0];
    __syncthreads();

    float e[8], sum = 0.f;
#pragma unroll
    for (int i = 0; i < 8; ++i) {
        e[i] = (j0 + i <= row) ? __expf(s[i] - m) : 0.f;
        sum += e[i];
    }
    red[tid] = sum;
    __syncthreads();
    for (int st = 128; st > 0; st >>= 1) {
        if (tid < st) red[tid] += red[tid + st];
        __syncthreads();
    }
    const float inv = 1.f / red[0];

    const int wcols = ((row >> 7) + 1) << 7;   // 128-aligned allowed width
    if (j0 < wcols) {
        i32x4 pk;
        pk[0] = (int)((unsigned)f2bf(e[0] * inv) | ((unsigned)f2bf(e[1] * inv) << 16));
        pk[1] = (int)((unsigned)f2bf(e[2] * inv) | ((unsigned)f2bf(e[3] * inv) << 16));
        pk[2] = (int)((unsigned)f2bf(e[4] * inv) | ((unsigned)f2bf(e[5] * inv) << 16));
        pk[3] = (int)((unsigned)f2bf(e[6] * inv) | ((unsigned)f2bf(e[7] * inv) << 16));
        *(i32x4*)((ushort*)base + j0) = pk;
    }
}

// W[z] [1024][1024] fp32 -> Wt3 + z*1M : bf16 [n][k] (transpose-convert)
__global__ __launch_bounds__(256) void cvt_wt(const float* __restrict__ Wq,
                                              const float* __restrict__ Wk,
                                              const float* __restrict__ Wv,
                                              ushort* __restrict__ Wt3)
{
    const float* W = (blockIdx.z == 0) ? Wq : (blockIdx.z == 1) ? Wk : Wv;
    ushort* Wt = Wt3 + (size_t)blockIdx.z * 1048576;

    __shared__ float t[32][33];
    const int tx = threadIdx.x & 31, ty = threadIdx.x >> 5;
    const int c = blockIdx.x * 32 + tx;
    const int rbase = blockIdx.y * 32;
#pragma unroll
    for (int i = 0; i < 4; ++i)
        t[ty + i * 8][tx] = W[(size_t)(rbase + ty + i * 8) * 1024 + c];
    __syncthreads();
    const int kT = blockIdx.y * 32 + tx;
    const int nT = blockIdx.x * 32;
#pragma unroll
    for (int i = 0; i < 4; ++i)
        Wt[(size_t)(nT + ty + i * 8) * 1024 + kT] = f2bf(t[tx][ty + i * 8]);
}

extern "C" void kernel_launch(void* const* d_in, const int* in_sizes, int n_in,
                              void* d_out, int out_size, void* d_ws, size_t ws_size,
                              hipStream_t stream)
{
    (void)in_sizes; (void)n_in; (void)out_size; (void)ws_size;

    const float* x  = (const float*)d_in[0];
    const float* Wq = (const float*)d_in[1];
    const float* Wk = (const float*)d_in[2];
    const float* Wv = (const float*)d_in[3];
    float* out = (float*)d_out;

    const int NB = 4, S = 2048, D = 1024;
    const long long SD  = (long long)S * D;     // 2,097,152
    const long long NSD = NB * SD;              // 8,388,608
    const long long SS  = (long long)S * S;     // 4,194,304

    // workspace (~133 MB): Wt3 | QKVb | Vt | Sc   (xb eliminated)
    ushort* Wt3  = (ushort*)d_ws;
    ushort* QKVb = Wt3  + 3 * (size_t)D * D;    // [8192][3072] bf16
    ushort* Vt   = QKVb + (size_t)NB * S * 3 * D;
    float*  Sc   = (float*)(Vt + NSD);          // NB*S*S fp32 (P overlays bf16)

    dim3 blk(256), blk5(512);

    // 1) W -> Wt3 (transpose-convert)
    cvt_wt<<<dim3(32, 32, 3), blk, 0, stream>>>(Wq, Wk, Wv, Wt3);

    // 2) merged QKV projection, A = x fp32 direct (reg-staged)
    dim3 gp(3 * D / 256, (unsigned)(NB * S / 128), 1);
    gemm_qkv<<<gp, blk5, 0, stream>>>(x, Wt3, QKVb);

    // 3) V -> Vt[b][d][s]
    transpose_v<<<dim3(D / 64, (unsigned)(NB * S / 64)), blk, 0, stream>>>(
        QKVb, Vt);

    // 4) scores = Q K^T / 32, 128x256 tiles, longest rows first
    dim3 gs(S / 256, S / 128, NB);
    gemm_bf16<128, 256, 1><<<gs, blk5, 0, stream>>>(
        QKVb, QKVb + 1024, Sc,
        S, D, 3 * D, 3 * D, (long long)S * 3 * D, (long long)S * 3 * D,
        SS, 0.03125f);

    // 5) softmax fp32 -> bf16 P in place (write-trimmed)
    softmax_bf16<<<dim3(S, NB), blk, 0, stream>>>(Sc);

    // 6) out = P V^T, 128x256 tiles, k-clipped, longest rows first
    dim3 gv(D / 256, S / 128, NB);
    gemm_bf16<128, 256, 2><<<gv, blk5, 0, stream>>>(
        (const ushort*)Sc, Vt, out,
        D, S, 2 * S, S, 2 * SS, SD, SD, 1.f);
}

// Round 13
// 200.937 us; speedup vs baseline: 1.0312x; 1.0312x over previous
//
#include <hip/hip_runtime.h>
#include <math.h>

// ---------------------------------------------------------------------------
// CausalAttention — round 13.
// r12 post-mortem: fp32-direct QKV regressed (FETCH 78->147MB: 12 column-
// blocks re-read the fp32 x-panel; bf16 xb was L3-friendly). Recombined:
//   * QKV path restored to r11 (cvt_x bf16 + gemm_bf16 OUT1, 71.7us proven).
//   * softmax keeps r12's write-trim (((row>>7)+1)<<7 cols = PV's k-clip
//     read region) and ADDS read-trim (j0 > row skips the fp32 load).
// QK/PV: r11 single-barrier counted-vmcnt GEMM (measured == r7 2-barrier).
// ---------------------------------------------------------------------------

typedef float  f32x4  __attribute__((ext_vector_type(4)));
typedef int    i32x4  __attribute__((ext_vector_type(4)));
typedef __bf16 bf16x8 __attribute__((ext_vector_type(8)));

__device__ inline ushort f2bf(float f) {
    union { float f; unsigned u; } a; a.f = f;
    unsigned u = a.u;
    return (ushort)((u + 0x7fffu + ((u >> 16) & 1u)) >> 16);  // RNE
}
__device__ inline bf16x8 as_bf(i32x4 v) {
    union { i32x4 i; bf16x8 b; } u; u.i = v; return u.b;
}

#define GLDS(gp, lp)                                                         \
    __builtin_amdgcn_global_load_lds(                                        \
        (const __attribute__((address_space(1))) void*)(gp),                 \
        (__attribute__((address_space(3))) void*)(lp), 16, 0, 0)

#define BKK 32

// 16B-chunk XOR swizzle within a 64B LDS row (involution; 0 conflicts, r5)
__device__ inline int swz(int row, int c) { return c ^ ((row >> 1) & 3); }

// MODE 0: plain  1: causal block-skip (scores)  2: k-clip (PV)
// OUT  0: fp32 C[z][r][c] = v*alpha     OUT 1: bf16 C[r][c] (merged QKV)
template <int BMT, int BNT, int MODE, int OUT>
__global__ __launch_bounds__((BMT / 64) * (BNT / 64) * 64,
                             ((BMT / 64) * (BNT / 64) == 8) ? 4 : 3)
void gemm_bf16(
    const ushort* __restrict__ A, const ushort* __restrict__ B0,
    float* __restrict__ Cf, ushort* __restrict__ Cb,
    int N, int K, int lda, int ldb,
    long long sA, long long sB, long long sC, float alpha)
{
    constexpr int NWC = BNT / 64;
    constexpr int T   = (BMT / 64) * NWC * 64;
    constexpr int RPG = T / 4;                // rows covered per GLDS issue
    constexpr int IA  = BMT / RPG;
    constexpr int IB  = BNT / RPG;
    constexpr int L   = IA + IB;              // GLDS per thread per tile
    static_assert(L == 3 || L == 4, "gate literals cover L=3,4");

    A  += (long long)blockIdx.z * sA;
    B0 += (long long)blockIdx.z * sB;

    int byi = blockIdx.y;
    if (MODE != 0) byi = gridDim.y - 1 - byi;   // longest row-blocks first

    const int m0 = byi * BMT;
    const int n0 = blockIdx.x * BNT;
    if (MODE == 1 && n0 > m0 + (BMT - 1)) return;
    int kend = K;
    if (MODE == 2) kend = min(K, m0 + BMT);     // attn weights 0 beyond

    __shared__ ushort As[3][BMT * BKK];
    __shared__ ushort Bs[3][BNT * BKK];

    const int tid = threadIdx.x;
    const int l   = tid & 63;
    const int w   = tid >> 6;
    const int g   = l >> 4;
    const int r16 = l & 15;
    const int wr  = w / NWC, wc = w % NWC;

    f32x4 acc[4][4];
#pragma unroll
    for (int mi = 0; mi < 4; ++mi)
#pragma unroll
        for (int ni = 0; ni < 4; ++ni)
            acc[mi][ni] = (f32x4){0.f, 0.f, 0.f, 0.f};

    const int srow = w * 16 + (l >> 2);
    const int cg   = swz(srow, l & 3);
    const ushort* gA = A  + (size_t)(m0 + srow) * lda + cg * 8;
    const ushort* gB = B0 + (size_t)(n0 + srow) * ldb + cg * 8;

#define STAGE(bi, k0)                                                        \
    do {                                                                     \
        _Pragma("unroll")                                                    \
        for (int ia = 0; ia < IA; ++ia)                                      \
            GLDS(gA + (k0) + (size_t)(ia * RPG) * lda,                       \
                 &As[bi][(ia * RPG + w * 16) * BKK]);                        \
        _Pragma("unroll")                                                    \
        for (int ib = 0; ib < IB; ++ib)                                      \
            GLDS(gB + (k0) + (size_t)(ib * RPG) * ldb,                       \
                 &Bs[bi][(ib * RPG + w * 16) * BKK]);                        \
    } while (0)

    const int nt = kend / BKK;
    STAGE(0, 0);
    if (nt > 1) STAGE(1, BKK);

    int cur = 0;
    for (int t = 0; t < nt; ++t) {
        // gate: tile t landed (t+1's L loads may stay in flight)
        if (t + 1 < nt) {
            if constexpr (L == 3)
                asm volatile("s_waitcnt vmcnt(3)" ::: "memory");
            else
                asm volatile("s_waitcnt vmcnt(4)" ::: "memory");
        } else {
            asm volatile("s_waitcnt vmcnt(0)" ::: "memory");
        }
        __builtin_amdgcn_s_barrier();   // tile-t visible; t-1 reads retired
        asm volatile("" ::: "memory");

        const int nxt = (cur >= 1) ? cur - 1 : 2;   // (t+2)%3 == (t-1)%3
        if (t + 2 < nt) STAGE(nxt, (t + 2) * BKK);  // flies under MFMA(t..t+1)

        i32x4 av[4], bv[4];
#pragma unroll
        for (int mi = 0; mi < 4; ++mi) {
            const int r = wr * 64 + mi * 16 + r16;
            av[mi] = *(const i32x4*)(&As[cur][r * BKK + swz(r, g) * 8]);
        }
#pragma unroll
        for (int ni = 0; ni < 4; ++ni) {
            const int r = wc * 64 + ni * 16 + r16;
            bv[ni] = *(const i32x4*)(&Bs[cur][r * BKK + swz(r, g) * 8]);
        }

        __builtin_amdgcn_s_setprio(1);
#pragma unroll
        for (int mi = 0; mi < 4; ++mi)
#pragma unroll
            for (int ni = 0; ni < 4; ++ni)
                acc[mi][ni] = __builtin_amdgcn_mfma_f32_16x16x32_bf16(
                    as_bf(av[mi]), as_bf(bv[ni]), acc[mi][ni], 0, 0, 0);
        __builtin_amdgcn_s_setprio(0);

        asm volatile("" ::: "memory");
        cur = (cur == 2) ? 0 : cur + 1;
    }
#undef STAGE

    // epilogue: C/D mapping col=lane&15, row=(lane>>4)*4+reg  [m89-verified]
#pragma unroll
    for (int mi = 0; mi < 4; ++mi) {
#pragma unroll
        for (int ni = 0; ni < 4; ++ni) {
#pragma unroll
            for (int rr = 0; rr < 4; ++rr) {
                const int gr = m0 + wr * 64 + mi * 16 + g * 4 + rr;
                const int gc = n0 + wc * 64 + ni * 16 + r16;
                const float v = acc[mi][ni][rr] * alpha;
                if (OUT == 0)
                    Cf[(long long)blockIdx.z * sC + (size_t)gr * N + gc] = v;
                else
                    Cb[(size_t)gr * N + gc] = f2bf(v);
            }
        }
    }
}

// V slice of merged QKV [8192][3072] (cols 2048..3071) -> Vt[b][d][s]
__global__ __launch_bounds__(256) void transpose_v(
    const ushort* __restrict__ QKV, ushort* __restrict__ Vt)
{
    __shared__ ushort t[64][65];
    const int d0 = blockIdx.x * 64;
    const int r0 = blockIdx.y * 64;          // b*2048+s, 64 | 2048
    const int tx = threadIdx.x & 31;
    const int ty = threadIdx.x >> 5;         // 0..7

#pragma unroll
    for (int p = 0; p < 8; ++p) {
        const int r = ty + p * 8;
        const ushort2 u = *(const ushort2*)(
            QKV + (size_t)(r0 + r) * 3072 + 2048 + d0 + 2 * tx);
        t[r][2 * tx]     = u.x;
        t[r][2 * tx + 1] = u.y;
    }
    __syncthreads();

    const int b = r0 >> 11, s0 = r0 & 2047;
#pragma unroll
    for (int p = 0; p < 8; ++p) {
        const int d = ty + p * 8;
        ushort2 o;
        o.x = t[2 * tx][d];
        o.y = t[2 * tx + 1][d];
        *(ushort2*)(Vt + (size_t)b * 2097152 + (size_t)(d0 + d) * 2048
                    + s0 + 2 * tx) = o;
    }
}

// fp32 scores -> bf16 P in place; 16B vector IO; read-trim (j0>row skips
// load) + write-trim to ((row>>7)+1)<<7 cols (= PV's k-clip read region).
__global__ __launch_bounds__(256) void softmax_bf16(float* __restrict__ Sc)
{
    const int row = blockIdx.x;
    float* base = Sc + ((size_t)blockIdx.y * 2048 + row) * 2048;
    const int tid = threadIdx.x;
    const int j0  = tid * 8;

    float s[8];
    if (j0 <= row) {
        const float4 a = *(const float4*)(base + j0);
        const float4 b = *(const float4*)(base + j0 + 4);
        s[0] = a.x; s[1] = a.y; s[2] = a.z; s[3] = a.w;
        s[4] = b.x; s[5] = b.y; s[6] = b.z; s[7] = b.w;
#pragma unroll
        for (int i = 0; i < 8; ++i)
            if (j0 + i > row) s[i] = -INFINITY;
    } else {
#pragma unroll
        for (int i = 0; i < 8; ++i) s[i] = -INFINITY;
    }

    __shared__ float red[256];
    float m = -INFINITY;
#pragma unroll
    for (int i = 0; i < 8; ++i) m = fmaxf(m, s[i]);
    red[tid] = m;
    __syncthreads();
    for (int st = 128; st > 0; st >>= 1) {
        if (tid < st) red[tid] = fmaxf(red[tid], red[tid + st]);
        __syncthreads();
    }
    m = red[0];
    __syncthreads();

    float e[8], sum = 0.f;
#pragma unroll
    for (int i = 0; i < 8; ++i) {
        e[i] = (j0 + i <= row) ? __expf(s[i] - m) : 0.f;
        sum += e[i];
    }
    red[tid] = sum;
    __syncthreads();
    for (int st = 128; st > 0; st >>= 1) {
        if (tid < st) red[tid] += red[tid + st];
        __syncthreads();
    }
    const float inv = 1.f / red[0];

    const int wcols = ((row >> 7) + 1) << 7;   // 128-aligned allowed width
    if (j0 < wcols) {
        i32x4 pk;
        pk[0] = (int)((unsigned)f2bf(e[0] * inv) | ((unsigned)f2bf(e[1] * inv) << 16));
        pk[1] = (int)((unsigned)f2bf(e[2] * inv) | ((unsigned)f2bf(e[3] * inv) << 16));
        pk[2] = (int)((unsigned)f2bf(e[4] * inv) | ((unsigned)f2bf(e[5] * inv) << 16));
        pk[3] = (int)((unsigned)f2bf(e[6] * inv) | ((unsigned)f2bf(e[7] * inv) << 16));
        *(i32x4*)((ushort*)base + j0) = pk;
    }
}

__global__ void cvt_x(const float4* __restrict__ x, ushort4* __restrict__ o, int n4)
{
    const int i = blockIdx.x * 256 + threadIdx.x;
    if (i < n4) {
        const float4 f = x[i];
        ushort4 u;
        u.x = f2bf(f.x); u.y = f2bf(f.y); u.z = f2bf(f.z); u.w = f2bf(f.w);
        o[i] = u;
    }
}

// W[z] [1024][1024] fp32 -> Wt3 + z*1M : bf16 [n][k] (transpose-convert)
__global__ __launch_bounds__(256) void cvt_wt(const float* __restrict__ Wq,
                                              const float* __restrict__ Wk,
                                              const float* __restrict__ Wv,
                                              ushort* __restrict__ Wt3)
{
    const float* W = (blockIdx.z == 0) ? Wq : (blockIdx.z == 1) ? Wk : Wv;
    ushort* Wt = Wt3 + (size_t)blockIdx.z * 1048576;

    __shared__ float t[32][33];
    const int tx = threadIdx.x & 31, ty = threadIdx.x >> 5;
    const int c = blockIdx.x * 32 + tx;
    const int rbase = blockIdx.y * 32;
#pragma unroll
    for (int i = 0; i < 4; ++i)
        t[ty + i * 8][tx] = W[(size_t)(rbase + ty + i * 8) * 1024 + c];
    __syncthreads();
    const int kT = blockIdx.y * 32 + tx;
    const int nT = blockIdx.x * 32;
#pragma unroll
    for (int i = 0; i < 4; ++i)
        Wt[(size_t)(nT + ty + i * 8) * 1024 + kT] = f2bf(t[tx][ty + i * 8]);
}

extern "C" void kernel_launch(void* const* d_in, const int* in_sizes, int n_in,
                              void* d_out, int out_size, void* d_ws, size_t ws_size,
                              hipStream_t stream)
{
    (void)in_sizes; (void)n_in; (void)out_size; (void)ws_size;

    const float* x  = (const float*)d_in[0];
    const float* Wq = (const float*)d_in[1];
    const float* Wk = (const float*)d_in[2];
    const float* Wv = (const float*)d_in[3];
    float* out = (float*)d_out;

    const int NB = 4, S = 2048, D = 1024;
    const long long SD  = (long long)S * D;     // 2,097,152
    const long long NSD = NB * SD;              // 8,388,608
    const long long SS  = (long long)S * S;     // 4,194,304

    // workspace (~150 MB): xb | Wt3 | QKVb | Vt | Sc
    ushort* xb   = (ushort*)d_ws;
    ushort* Wt3  = xb   + NSD;
    ushort* QKVb = Wt3  + 3 * (size_t)D * D;    // [8192][3072] bf16
    ushort* Vt   = QKVb + (size_t)NB * S * 3 * D;
    float*  Sc   = (float*)(Vt + NSD);          // NB*S*S fp32 (P overlays bf16)

    dim3 blk(256), blk5(512);

    // 1) conversions
    cvt_x<<<dim3((unsigned)(NSD / 4 / 256)), blk, 0, stream>>>(
        (const float4*)x, (ushort4*)xb, (int)(NSD / 4));
    cvt_wt<<<dim3(32, 32, 3), blk, 0, stream>>>(Wq, Wk, Wv, Wt3);

    // 2) merged QKV projection: [8192 x 3072 x 1024], 128x256 tiles
    dim3 gp(3 * D / 256, (unsigned)(NB * S / 128), 1);
    gemm_bf16<128, 256, 0, 1><<<gp, blk5, 0, stream>>>(
        xb, Wt3, nullptr, QKVb,
        3 * D, D, D, D, 0, 0, 0, 1.f);

    // 3) V -> Vt[b][d][s]
    transpose_v<<<dim3(D / 64, (unsigned)(NB * S / 64)), blk, 0, stream>>>(
        QKVb, Vt);

    // 4) scores = Q K^T / 32, 128x256 tiles, longest rows first
    dim3 gs(S / 256, S / 128, NB);
    gemm_bf16<128, 256, 1, 0><<<gs, blk5, 0, stream>>>(
        QKVb, QKVb + 1024, Sc, nullptr,
        S, D, 3 * D, 3 * D, (long long)S * 3 * D, (long long)S * 3 * D,
        SS, 0.03125f);

    // 5) softmax fp32 -> bf16 P in place (read+write trimmed)
    softmax_bf16<<<dim3(S, NB), blk, 0, stream>>>(Sc);

    // 6) out = P V^T, 128x256 tiles, k-clipped, longest rows first
    dim3 gv(D / 256, S / 128, NB);
    gemm_bf16<128, 256, 2, 0><<<gv, blk5, 0, stream>>>(
        (const ushort*)Sc, Vt, out, nullptr,
        D, S, 2 * S, S, 2 * SS, SD, SD, 1.f);
}

// Round 14
// 160.452 us; speedup vs baseline: 1.2914x; 1.2523x over previous
//
#include <hip/hip_runtime.h>
#include <math.h>

// ---------------------------------------------------------------------------
// CausalAttention — round 14.
// r13 = 200.9us (= r7 within noise). QKV plateaued ~71us across 5 structures
// (2-phase ceiling; 8-phase port deferred — can't race-screen headless).
// This round removes the V materialization round-trip:
//   * QKV V-column blocks (n0>=2048, uniform per block) transpose IN-EPILOGUE:
//     after K-loop the 72KB staging LDS is dead -> acc => T[d][s] (row stride
//     136 ushorts: 16B-aligned, 2-way-free banks), barrier, coalesced write
//     Vt[b][d][s] (16 lanes x 16B = one 256B d-row, full-line utilization).
//     V-blocks skip the QKVb write entirely (-17MB) ; transpose_v DELETED.
//   * Same f2bf path for V values -> absmax bit-identical.
// Everything else identical to r13 (single-barrier counted-vmcnt GEMM,
// trimmed softmax, cvt_x/cvt_wt, longest-first causal dispatch).
// ---------------------------------------------------------------------------

typedef float  f32x4  __attribute__((ext_vector_type(4)));
typedef int    i32x4  __attribute__((ext_vector_type(4)));
typedef __bf16 bf16x8 __attribute__((ext_vector_type(8)));

__device__ inline ushort f2bf(float f) {
    union { float f; unsigned u; } a; a.f = f;
    unsigned u = a.u;
    return (ushort)((u + 0x7fffu + ((u >> 16) & 1u)) >> 16);  // RNE
}
__device__ inline bf16x8 as_bf(i32x4 v) {
    union { i32x4 i; bf16x8 b; } u; u.i = v; return u.b;
}

#define GLDS(gp, lp)                                                         \
    __builtin_amdgcn_global_load_lds(                                        \
        (const __attribute__((address_space(1))) void*)(gp),                 \
        (__attribute__((address_space(3))) void*)(lp), 16, 0, 0)

#define BKK 32

// 16B-chunk XOR swizzle within a 64B LDS row (involution; 0 conflicts, r5)
__device__ inline int swz(int row, int c) { return c ^ ((row >> 1) & 3); }

// MODE 0: plain  1: causal block-skip (scores)  2: k-clip (PV)
// OUT  0: fp32 C[z][r][c] = v*alpha
// OUT  1: merged QKV: Q/K cols -> bf16 Cb[r][c]; V cols -> Vt[b][d][s]
//         via in-LDS transpose (staging LDS reused as T after the K-loop).
template <int BMT, int BNT, int MODE, int OUT>
__global__ __launch_bounds__((BMT / 64) * (BNT / 64) * 64,
                             ((BMT / 64) * (BNT / 64) == 8) ? 4 : 3)
void gemm_bf16(
    const ushort* __restrict__ A, const ushort* __restrict__ B0,
    float* __restrict__ Cf, ushort* __restrict__ Cb, ushort* __restrict__ Vt,
    int N, int K, int lda, int ldb,
    long long sA, long long sB, long long sC, float alpha)
{
    constexpr int NWC = BNT / 64;
    constexpr int T   = (BMT / 64) * NWC * 64;
    constexpr int RPG = T / 4;                // rows covered per GLDS issue
    constexpr int IA  = BMT / RPG;
    constexpr int IB  = BNT / RPG;
    constexpr int L   = IA + IB;              // GLDS per thread per tile
    static_assert(L == 3 || L == 4, "gate literals cover L=3,4");

    // one LDS arena: A tri-buffer | B tri-buffer (carved by address math)
    __shared__ ushort SH[3 * BMT * BKK + 3 * BNT * BKK];
#define ASB(bi) (SH + (bi) * (BMT * BKK))
#define BSB(bi) (SH + 3 * (BMT * BKK) + (bi) * (BNT * BKK))

    A  += (long long)blockIdx.z * sA;
    B0 += (long long)blockIdx.z * sB;

    int byi = blockIdx.y;
    if (MODE != 0) byi = gridDim.y - 1 - byi;   // longest row-blocks first

    const int m0 = byi * BMT;
    const int n0 = blockIdx.x * BNT;
    if (MODE == 1 && n0 > m0 + (BMT - 1)) return;
    int kend = K;
    if (MODE == 2) kend = min(K, m0 + BMT);     // attn weights 0 beyond

    const int tid = threadIdx.x;
    const int l   = tid & 63;
    const int w   = tid >> 6;
    const int g   = l >> 4;
    const int r16 = l & 15;
    const int wr  = w / NWC, wc = w % NWC;

    f32x4 acc[4][4];
#pragma unroll
    for (int mi = 0; mi < 4; ++mi)
#pragma unroll
        for (int ni = 0; ni < 4; ++ni)
            acc[mi][ni] = (f32x4){0.f, 0.f, 0.f, 0.f};

    const int srow = w * 16 + (l >> 2);
    const int cg   = swz(srow, l & 3);
    const ushort* gA = A  + (size_t)(m0 + srow) * lda + cg * 8;
    const ushort* gB = B0 + (size_t)(n0 + srow) * ldb + cg * 8;

#define STAGE(bi, k0)                                                        \
    do {                                                                     \
        _Pragma("unroll")                                                    \
        for (int ia = 0; ia < IA; ++ia)                                      \
            GLDS(gA + (k0) + (size_t)(ia * RPG) * lda,                       \
                 ASB(bi) + (ia * RPG + w * 16) * BKK);                       \
        _Pragma("unroll")                                                    \
        for (int ib = 0; ib < IB; ++ib)                                      \
            GLDS(gB + (k0) + (size_t)(ib * RPG) * ldb,                       \
                 BSB(bi) + (ib * RPG + w * 16) * BKK);                       \
    } while (0)

    const int nt = kend / BKK;
    STAGE(0, 0);
    if (nt > 1) STAGE(1, BKK);

    int cur = 0;
    for (int t = 0; t < nt; ++t) {
        if (t + 1 < nt) {       // tile t landed; t+1's L loads stay in flight
            if constexpr (L == 3)
                asm volatile("s_waitcnt vmcnt(3)" ::: "memory");
            else
                asm volatile("s_waitcnt vmcnt(4)" ::: "memory");
        } else {
            asm volatile("s_waitcnt vmcnt(0)" ::: "memory");
        }
        __builtin_amdgcn_s_barrier();   // tile-t visible; t-1 reads retired
        asm volatile("" ::: "memory");

        const int nxt = (cur >= 1) ? cur - 1 : 2;   // (t+2)%3 == (t-1)%3
        if (t + 2 < nt) STAGE(nxt, (t + 2) * BKK);  // flies under MFMA(t..t+1)

        const ushort* Ab = ASB(cur);
        const ushort* Bb = BSB(cur);
        i32x4 av[4], bv[4];
#pragma unroll
        for (int mi = 0; mi < 4; ++mi) {
            const int r = wr * 64 + mi * 16 + r16;
            av[mi] = *(const i32x4*)(Ab + r * BKK + swz(r, g) * 8);
        }
#pragma unroll
        for (int ni = 0; ni < 4; ++ni) {
            const int r = wc * 64 + ni * 16 + r16;
            bv[ni] = *(const i32x4*)(Bb + r * BKK + swz(r, g) * 8);
        }

        __builtin_amdgcn_s_setprio(1);
#pragma unroll
        for (int mi = 0; mi < 4; ++mi)
#pragma unroll
            for (int ni = 0; ni < 4; ++ni)
                acc[mi][ni] = __builtin_amdgcn_mfma_f32_16x16x32_bf16(
                    as_bf(av[mi]), as_bf(bv[ni]), acc[mi][ni], 0, 0, 0);
        __builtin_amdgcn_s_setprio(0);

        asm volatile("" ::: "memory");
        cur = (cur == 2) ? 0 : cur + 1;
    }
#undef STAGE

    if constexpr (OUT == 1) {
        if (n0 >= 2048) {
            // ---- V-region: in-LDS transpose, coalesced Vt[b][d][s] write.
            // T[d][s]: 256 x 136-ushort rows (272B: 16B-aligned, banks 2-way).
            ushort* Tb = SH;
            __builtin_amdgcn_s_barrier();   // all K-loop LDS reads retired
            asm volatile("" ::: "memory");
#pragma unroll
            for (int mi = 0; mi < 4; ++mi) {
#pragma unroll
                for (int ni = 0; ni < 4; ++ni) {
                    const int c0 = wc * 64 + ni * 16 + r16;      // d_local
                    const int r0 = wr * 64 + mi * 16 + g * 4;    // s_local
                    ushort4 pk;
                    pk.x = f2bf(acc[mi][ni][0]);
                    pk.y = f2bf(acc[mi][ni][1]);
                    pk.z = f2bf(acc[mi][ni][2]);
                    pk.w = f2bf(acc[mi][ni][3]);
                    *(ushort4*)&Tb[c0 * 136 + r0] = pk;
                }
            }
            asm volatile("" ::: "memory");
            __builtin_amdgcn_s_barrier();   // T complete
            asm volatile("" ::: "memory");

            const int bb = m0 >> 11, s0 = m0 & 2047;
            const int dl = tid >> 4;          // 0..31
            const int sc = (tid & 15) * 8;    // s chunk (8 ushorts = 16B)
#pragma unroll
            for (int p = 0; p < 8; ++p) {
                const int d = p * 32 + dl;
                const i32x4 v = *(const i32x4*)&Tb[d * 136 + sc];
                *(i32x4*)(Vt + (size_t)bb * 2097152
                          + (size_t)(n0 - 2048 + d) * 2048 + s0 + sc) = v;
            }
            return;
        }
        // ---- Q/K region: plain bf16 row-major write
#pragma unroll
        for (int mi = 0; mi < 4; ++mi)
#pragma unroll
            for (int ni = 0; ni < 4; ++ni)
#pragma unroll
                for (int rr = 0; rr < 4; ++rr) {
                    const int gr = m0 + wr * 64 + mi * 16 + g * 4 + rr;
                    const int gc = n0 + wc * 64 + ni * 16 + r16;
                    Cb[(size_t)gr * N + gc] = f2bf(acc[mi][ni][rr]);
                }
        return;
    }

    // OUT == 0: fp32 C = v * alpha
#pragma unroll
    for (int mi = 0; mi < 4; ++mi)
#pragma unroll
        for (int ni = 0; ni < 4; ++ni)
#pragma unroll
            for (int rr = 0; rr < 4; ++rr) {
                const int gr = m0 + wr * 64 + mi * 16 + g * 4 + rr;
                const int gc = n0 + wc * 64 + ni * 16 + r16;
                Cf[(long long)blockIdx.z * sC + (size_t)gr * N + gc] =
                    acc[mi][ni][rr] * alpha;
            }
#undef ASB
#undef BSB
}

// fp32 scores -> bf16 P in place; 16B vector IO; read-trim (j0>row skips
// load) + write-trim to ((row>>7)+1)<<7 cols (= PV's k-clip read region).
__global__ __launch_bounds__(256) void softmax_bf16(float* __restrict__ Sc)
{
    const int row = blockIdx.x;
    float* base = Sc + ((size_t)blockIdx.y * 2048 + row) * 2048;
    const int tid = threadIdx.x;
    const int j0  = tid * 8;

    float s[8];
    if (j0 <= row) {
        const float4 a = *(const float4*)(base + j0);
        const float4 b = *(const float4*)(base + j0 + 4);
        s[0] = a.x; s[1] = a.y; s[2] = a.z; s[3] = a.w;
        s[4] = b.x; s[5] = b.y; s[6] = b.z; s[7] = b.w;
#pragma unroll
        for (int i = 0; i < 8; ++i)
            if (j0 + i > row) s[i] = -INFINITY;
    } else {
#pragma unroll
        for (int i = 0; i < 8; ++i) s[i] = -INFINITY;
    }

    __shared__ float red[256];
    float m = -INFINITY;
#pragma unroll
    for (int i = 0; i < 8; ++i) m = fmaxf(m, s[i]);
    red[tid] = m;
    __syncthreads();
    for (int st = 128; st > 0; st >>= 1) {
        if (tid < st) red[tid] = fmaxf(red[tid], red[tid + st]);
        __syncthreads();
    }
    m = red[0];
    __syncthreads();

    float e[8], sum = 0.f;
#pragma unroll
    for (int i = 0; i < 8; ++i) {
        e[i] = (j0 + i <= row) ? __expf(s[i] - m) : 0.f;
        sum += e[i];
    }
    red[tid] = sum;
    __syncthreads();
    for (int st = 128; st > 0; st >>= 1) {
        if (tid < st) red[tid] += red[tid + st];
        __syncthreads();
    }
    const float inv = 1.f / red[0];

    const int wcols = ((row >> 7) + 1) << 7;   // 128-aligned allowed width
    if (j0 < wcols) {
        i32x4 pk;
        pk[0] = (int)((unsigned)f2bf(e[0] * inv) | ((unsigned)f2bf(e[1] * inv) << 16));
        pk[1] = (int)((unsigned)f2bf(e[2] * inv) | ((unsigned)f2bf(e[3] * inv) << 16));
        pk[2] = (int)((unsigned)f2bf(e[4] * inv) | ((unsigned)f2bf(e[5] * inv) << 16));
        pk[3] = (int)((unsigned)f2bf(e[6] * inv) | ((unsigned)f2bf(e[7] * inv) << 16));
        *(i32x4*)((ushort*)base + j0) = pk;
    }
}

__global__ void cvt_x(const float4* __restrict__ x, ushort4* __restrict__ o, int n4)
{
    const int i = blockIdx.x * 256 + threadIdx.x;
    if (i < n4) {
        const float4 f = x[i];
        ushort4 u;
        u.x = f2bf(f.x); u.y = f2bf(f.y); u.z = f2bf(f.z); u.w = f2bf(f.w);
        o[i] = u;
    }
}

// W[z] [1024][1024] fp32 -> Wt3 + z*1M : bf16 [n][k] (transpose-convert)
__global__ __launch_bounds__(256) void cvt_wt(const float* __restrict__ Wq,
                                              const float* __restrict__ Wk,
                                              const float* __restrict__ Wv,
                                              ushort* __restrict__ Wt3)
{
    const float* W = (blockIdx.z == 0) ? Wq : (blockIdx.z == 1) ? Wk : Wv;
    ushort* Wt = Wt3 + (size_t)blockIdx.z * 1048576;

    __shared__ float t[32][33];
    const int tx = threadIdx.x & 31, ty = threadIdx.x >> 5;
    const int c = blockIdx.x * 32 + tx;
    const int rbase = blockIdx.y * 32;
#pragma unroll
    for (int i = 0; i < 4; ++i)
        t[ty + i * 8][tx] = W[(size_t)(rbase + ty + i * 8) * 1024 + c];
    __syncthreads();
    const int kT = blockIdx.y * 32 + tx;
    const int nT = blockIdx.x * 32;
#pragma unroll
    for (int i = 0; i < 4; ++i)
        Wt[(size_t)(nT + ty + i * 8) * 1024 + kT] = f2bf(t[tx][ty + i * 8]);
}

extern "C" void kernel_launch(void* const* d_in, const int* in_sizes, int n_in,
                              void* d_out, int out_size, void* d_ws, size_t ws_size,
                              hipStream_t stream)
{
    (void)in_sizes; (void)n_in; (void)out_size; (void)ws_size;

    const float* x  = (const float*)d_in[0];
    const float* Wq = (const float*)d_in[1];
    const float* Wk = (const float*)d_in[2];
    const float* Wv = (const float*)d_in[3];
    float* out = (float*)d_out;

    const int NB = 4, S = 2048, D = 1024;
    const long long SD  = (long long)S * D;     // 2,097,152
    const long long NSD = NB * SD;              // 8,388,608
    const long long SS  = (long long)S * S;     // 4,194,304

    // workspace (~150 MB): xb | Wt3 | QKVb | Vt | Sc
    ushort* xb   = (ushort*)d_ws;
    ushort* Wt3  = xb   + NSD;
    ushort* QKVb = Wt3  + 3 * (size_t)D * D;    // [8192][3072] bf16 (Q/K used)
    ushort* Vt   = QKVb + (size_t)NB * S * 3 * D;
    float*  Sc   = (float*)(Vt + NSD);          // NB*S*S fp32 (P overlays bf16)

    dim3 blk(256), blk5(512);

    // 1) conversions
    cvt_x<<<dim3((unsigned)(NSD / 4 / 256)), blk, 0, stream>>>(
        (const float4*)x, (ushort4*)xb, (int)(NSD / 4));
    cvt_wt<<<dim3(32, 32, 3), blk, 0, stream>>>(Wq, Wk, Wv, Wt3);

    // 2) merged QKV projection; V columns transposed in-epilogue -> Vt
    dim3 gp(3 * D / 256, (unsigned)(NB * S / 128), 1);
    gemm_bf16<128, 256, 0, 1><<<gp, blk5, 0, stream>>>(
        xb, Wt3, nullptr, QKVb, Vt,
        3 * D, D, D, D, 0, 0, 0, 1.f);

    // 3) scores = Q K^T / 32, 128x256 tiles, longest rows first
    dim3 gs(S / 256, S / 128, NB);
    gemm_bf16<128, 256, 1, 0><<<gs, blk5, 0, stream>>>(
        QKVb, QKVb + 1024, Sc, nullptr, nullptr,
        S, D, 3 * D, 3 * D, (long long)S * 3 * D, (long long)S * 3 * D,
        SS, 0.03125f);

    // 4) softmax fp32 -> bf16 P in place (read+write trimmed)
    softmax_bf16<<<dim3(S, NB), blk, 0, stream>>>(Sc);

    // 5) out = P V^T, 128x256 tiles, k-clipped, longest rows first
    dim3 gv(D / 256, S / 128, NB);
    gemm_bf16<128, 256, 2, 0><<<gv, blk5, 0, stream>>>(
        (const ushort*)Sc, Vt, out, nullptr, nullptr,
        D, S, 2 * S, S, 2 * SS, SD, SD, 1.f);
}

// Round 15
// 158.182 us; speedup vs baseline: 1.3099x; 1.0144x over previous
//
#include <hip/hip_runtime.h>
#include <math.h>

// ---------------------------------------------------------------------------
// CausalAttention — round 15 (consolidation on the r14 win: 160.5us).
//   * QKV: bijective XCD chunk-swizzle (768 blocks % 8 == 0; code path proven
//     correct in r8). Each XCD gets 96 contiguous flat ids = 8 full A-row
//     panels -> x-panel reuse in per-XCD L2.
//   * cvt_x + cvt_wt merged into one cvt_all launch (block-uniform branch).
//   * Everything else byte-identical to r14: single-barrier counted-vmcnt
//     tri-buffer GEMM, in-epilogue V transpose -> Vt, trimmed softmax,
//     longest-first causal dispatch.
// 8-phase 256^2 schedule (MfmaUtil 35->60%) deliberately NOT attempted:
// new sync template, cannot race-screen headless (m152).
// ---------------------------------------------------------------------------

typedef float  f32x4  __attribute__((ext_vector_type(4)));
typedef int    i32x4  __attribute__((ext_vector_type(4)));
typedef __bf16 bf16x8 __attribute__((ext_vector_type(8)));

__device__ inline ushort f2bf(float f) {
    union { float f; unsigned u; } a; a.f = f;
    unsigned u = a.u;
    return (ushort)((u + 0x7fffu + ((u >> 16) & 1u)) >> 16);  // RNE
}
__device__ inline bf16x8 as_bf(i32x4 v) {
    union { i32x4 i; bf16x8 b; } u; u.i = v; return u.b;
}

#define GLDS(gp, lp)                                                         \
    __builtin_amdgcn_global_load_lds(                                        \
        (const __attribute__((address_space(1))) void*)(gp),                 \
        (__attribute__((address_space(3))) void*)(lp), 16, 0, 0)

#define BKK 32

// 16B-chunk XOR swizzle within a 64B LDS row (involution; 0 conflicts, r5)
__device__ inline int swz(int row, int c) { return c ^ ((row >> 1) & 3); }

// MODE 0: plain  1: causal block-skip (scores)  2: k-clip (PV)
// OUT  0: fp32 C[z][r][c] = v*alpha
// OUT  1: merged QKV: Q/K cols -> bf16 Cb[r][c]; V cols -> Vt[b][d][s]
//         via in-LDS transpose; XCD chunk-swizzled blockIdx.
template <int BMT, int BNT, int MODE, int OUT>
__global__ __launch_bounds__((BMT / 64) * (BNT / 64) * 64,
                             ((BMT / 64) * (BNT / 64) == 8) ? 4 : 3)
void gemm_bf16(
    const ushort* __restrict__ A, const ushort* __restrict__ B0,
    float* __restrict__ Cf, ushort* __restrict__ Cb, ushort* __restrict__ Vt,
    int N, int K, int lda, int ldb,
    long long sA, long long sB, long long sC, float alpha)
{
    constexpr int NWC = BNT / 64;
    constexpr int T   = (BMT / 64) * NWC * 64;
    constexpr int RPG = T / 4;                // rows covered per GLDS issue
    constexpr int IA  = BMT / RPG;
    constexpr int IB  = BNT / RPG;
    constexpr int L   = IA + IB;              // GLDS per thread per tile
    static_assert(L == 3 || L == 4, "gate literals cover L=3,4");

    // one LDS arena: A tri-buffer | B tri-buffer (carved by address math)
    __shared__ ushort SH[3 * BMT * BKK + 3 * BNT * BKK];
#define ASB(bi) (SH + (bi) * (BMT * BKK))
#define BSB(bi) (SH + 3 * (BMT * BKK) + (bi) * (BNT * BKK))

    A  += (long long)blockIdx.z * sA;
    B0 += (long long)blockIdx.z * sB;

    int bx = blockIdx.x, byi = blockIdx.y;
    if (OUT == 1) {
        // bijective XCD chunk swizzle (nwg = gx*gy, multiple of 8)
        const int nwg = (int)(gridDim.x * gridDim.y);
        int flat = byi * (int)gridDim.x + bx;
        flat = (flat & 7) * (nwg >> 3) + (flat >> 3);
        bx  = flat % (int)gridDim.x;
        byi = flat / (int)gridDim.x;
    }
    if (MODE != 0) byi = (int)gridDim.y - 1 - byi;   // longest rows first

    const int m0 = byi * BMT;
    const int n0 = bx * BNT;
    if (MODE == 1 && n0 > m0 + (BMT - 1)) return;
    int kend = K;
    if (MODE == 2) kend = min(K, m0 + BMT);     // attn weights 0 beyond

    const int tid = threadIdx.x;
    const int l   = tid & 63;
    const int w   = tid >> 6;
    const int g   = l >> 4;
    const int r16 = l & 15;
    const int wr  = w / NWC, wc = w % NWC;

    f32x4 acc[4][4];
#pragma unroll
    for (int mi = 0; mi < 4; ++mi)
#pragma unroll
        for (int ni = 0; ni < 4; ++ni)
            acc[mi][ni] = (f32x4){0.f, 0.f, 0.f, 0.f};

    const int srow = w * 16 + (l >> 2);
    const int cg   = swz(srow, l & 3);
    const ushort* gA = A  + (size_t)(m0 + srow) * lda + cg * 8;
    const ushort* gB = B0 + (size_t)(n0 + srow) * ldb + cg * 8;

#define STAGE(bi, k0)                                                        \
    do {                                                                     \
        _Pragma("unroll")                                                    \
        for (int ia = 0; ia < IA; ++ia)                                      \
            GLDS(gA + (k0) + (size_t)(ia * RPG) * lda,                       \
                 ASB(bi) + (ia * RPG + w * 16) * BKK);                       \
        _Pragma("unroll")                                                    \
        for (int ib = 0; ib < IB; ++ib)                                      \
            GLDS(gB + (k0) + (size_t)(ib * RPG) * ldb,                       \
                 BSB(bi) + (ib * RPG + w * 16) * BKK);                       \
    } while (0)

    const int nt = kend / BKK;
    STAGE(0, 0);
    if (nt > 1) STAGE(1, BKK);

    int cur = 0;
    for (int t = 0; t < nt; ++t) {
        if (t + 1 < nt) {       // tile t landed; t+1's L loads stay in flight
            if constexpr (L == 3)
                asm volatile("s_waitcnt vmcnt(3)" ::: "memory");
            else
                asm volatile("s_waitcnt vmcnt(4)" ::: "memory");
        } else {
            asm volatile("s_waitcnt vmcnt(0)" ::: "memory");
        }
        __builtin_amdgcn_s_barrier();   // tile-t visible; t-1 reads retired
        asm volatile("" ::: "memory");

        const int nxt = (cur >= 1) ? cur - 1 : 2;   // (t+2)%3 == (t-1)%3
        if (t + 2 < nt) STAGE(nxt, (t + 2) * BKK);  // flies under MFMA(t..t+1)

        const ushort* Ab = ASB(cur);
        const ushort* Bb = BSB(cur);
        i32x4 av[4], bv[4];
#pragma unroll
        for (int mi = 0; mi < 4; ++mi) {
            const int r = wr * 64 + mi * 16 + r16;
            av[mi] = *(const i32x4*)(Ab + r * BKK + swz(r, g) * 8);
        }
#pragma unroll
        for (int ni = 0; ni < 4; ++ni) {
            const int r = wc * 64 + ni * 16 + r16;
            bv[ni] = *(const i32x4*)(Bb + r * BKK + swz(r, g) * 8);
        }

        __builtin_amdgcn_s_setprio(1);
#pragma unroll
        for (int mi = 0; mi < 4; ++mi)
#pragma unroll
            for (int ni = 0; ni < 4; ++ni)
                acc[mi][ni] = __builtin_amdgcn_mfma_f32_16x16x32_bf16(
                    as_bf(av[mi]), as_bf(bv[ni]), acc[mi][ni], 0, 0, 0);
        __builtin_amdgcn_s_setprio(0);

        asm volatile("" ::: "memory");
        cur = (cur == 2) ? 0 : cur + 1;
    }
#undef STAGE

    if constexpr (OUT == 1) {
        if (n0 >= 2048) {
            // ---- V-region: in-LDS transpose, coalesced Vt[b][d][s] write.
            ushort* Tb = SH;
            __builtin_amdgcn_s_barrier();   // all K-loop LDS reads retired
            asm volatile("" ::: "memory");
#pragma unroll
            for (int mi = 0; mi < 4; ++mi) {
#pragma unroll
                for (int ni = 0; ni < 4; ++ni) {
                    const int c0 = wc * 64 + ni * 16 + r16;      // d_local
                    const int r0 = wr * 64 + mi * 16 + g * 4;    // s_local
                    ushort4 pk;
                    pk.x = f2bf(acc[mi][ni][0]);
                    pk.y = f2bf(acc[mi][ni][1]);
                    pk.z = f2bf(acc[mi][ni][2]);
                    pk.w = f2bf(acc[mi][ni][3]);
                    *(ushort4*)&Tb[c0 * 136 + r0] = pk;
                }
            }
            asm volatile("" ::: "memory");
            __builtin_amdgcn_s_barrier();   // T complete
            asm volatile("" ::: "memory");

            const int bb = m0 >> 11, s0 = m0 & 2047;
            const int dl = tid >> 4;          // 0..31
            const int sc = (tid & 15) * 8;    // s chunk (8 ushorts = 16B)
#pragma unroll
            for (int p = 0; p < 8; ++p) {
                const int d = p * 32 + dl;
                const i32x4 v = *(const i32x4*)&Tb[d * 136 + sc];
                *(i32x4*)(Vt + (size_t)bb * 2097152
                          + (size_t)(n0 - 2048 + d) * 2048 + s0 + sc) = v;
            }
            return;
        }
        // ---- Q/K region: plain bf16 row-major write
#pragma unroll
        for (int mi = 0; mi < 4; ++mi)
#pragma unroll
            for (int ni = 0; ni < 4; ++ni)
#pragma unroll
                for (int rr = 0; rr < 4; ++rr) {
                    const int gr = m0 + wr * 64 + mi * 16 + g * 4 + rr;
                    const int gc = n0 + wc * 64 + ni * 16 + r16;
                    Cb[(size_t)gr * N + gc] = f2bf(acc[mi][ni][rr]);
                }
        return;
    }

    // OUT == 0: fp32 C = v * alpha
#pragma unroll
    for (int mi = 0; mi < 4; ++mi)
#pragma unroll
        for (int ni = 0; ni < 4; ++ni)
#pragma unroll
            for (int rr = 0; rr < 4; ++rr) {
                const int gr = m0 + wr * 64 + mi * 16 + g * 4 + rr;
                const int gc = n0 + wc * 64 + ni * 16 + r16;
                Cf[(long long)blockIdx.z * sC + (size_t)gr * N + gc] =
                    acc[mi][ni][rr] * alpha;
            }
#undef ASB
#undef BSB
}

// fp32 scores -> bf16 P in place; 16B vector IO; read-trim (j0>row skips
// load) + write-trim to ((row>>7)+1)<<7 cols (= PV's k-clip read region).
__global__ __launch_bounds__(256) void softmax_bf16(float* __restrict__ Sc)
{
    const int row = blockIdx.x;
    float* base = Sc + ((size_t)blockIdx.y * 2048 + row) * 2048;
    const int tid = threadIdx.x;
    const int j0  = tid * 8;

    float s[8];
    if (j0 <= row) {
        const float4 a = *(const float4*)(base + j0);
        const float4 b = *(const float4*)(base + j0 + 4);
        s[0] = a.x; s[1] = a.y; s[2] = a.z; s[3] = a.w;
        s[4] = b.x; s[5] = b.y; s[6] = b.z; s[7] = b.w;
#pragma unroll
        for (int i = 0; i < 8; ++i)
            if (j0 + i > row) s[i] = -INFINITY;
    } else {
#pragma unroll
        for (int i = 0; i < 8; ++i) s[i] = -INFINITY;
    }

    __shared__ float red[256];
    float m = -INFINITY;
#pragma unroll
    for (int i = 0; i < 8; ++i) m = fmaxf(m, s[i]);
    red[tid] = m;
    __syncthreads();
    for (int st = 128; st > 0; st >>= 1) {
        if (tid < st) red[tid] = fmaxf(red[tid], red[tid + st]);
        __syncthreads();
    }
    m = red[0];
    __syncthreads();

    float e[8], sum = 0.f;
#pragma unroll
    for (int i = 0; i < 8; ++i) {
        e[i] = (j0 + i <= row) ? __expf(s[i] - m) : 0.f;
        sum += e[i];
    }
    red[tid] = sum;
    __syncthreads();
    for (int st = 128; st > 0; st >>= 1) {
        if (tid < st) red[tid] += red[tid + st];
        __syncthreads();
    }
    const float inv = 1.f / red[0];

    const int wcols = ((row >> 7) + 1) << 7;   // 128-aligned allowed width
    if (j0 < wcols) {
        i32x4 pk;
        pk[0] = (int)((unsigned)f2bf(e[0] * inv) | ((unsigned)f2bf(e[1] * inv) << 16));
        pk[1] = (int)((unsigned)f2bf(e[2] * inv) | ((unsigned)f2bf(e[3] * inv) << 16));
        pk[2] = (int)((unsigned)f2bf(e[4] * inv) | ((unsigned)f2bf(e[5] * inv) << 16));
        pk[3] = (int)((unsigned)f2bf(e[6] * inv) | ((unsigned)f2bf(e[7] * inv) << 16));
        *(i32x4*)((ushort*)base + j0) = pk;
    }
}

// Merged conversions (one launch):
//   blocks [0, 8192)      : x fp32 -> xb bf16 (float4/ushort4)
//   blocks [8192, 11264)  : W[z] [1024][1024] -> Wt3+z*1M bf16 [n][k]
__global__ __launch_bounds__(256) void cvt_all(
    const float4* __restrict__ x4, ushort4* __restrict__ xb4,
    const float* __restrict__ Wq, const float* __restrict__ Wk,
    const float* __restrict__ Wv, ushort* __restrict__ Wt3)
{
    const int b = blockIdx.x;
    if (b < 8192) {
        const int i = b * 256 + threadIdx.x;   // < 8,388,608/4 always
        const float4 f = x4[i];
        ushort4 u;
        u.x = f2bf(f.x); u.y = f2bf(f.y); u.z = f2bf(f.z); u.w = f2bf(f.w);
        xb4[i] = u;
        return;
    }
    const int t  = b - 8192;          // 0..3071
    const int z  = t >> 10;           // 0..2
    const int r  = t & 1023;
    const int bxw = r & 31, byw = r >> 5;

    const float* W = (z == 0) ? Wq : (z == 1) ? Wk : Wv;
    ushort* Wt = Wt3 + (size_t)z * 1048576;

    __shared__ float tle[32][33];
    const int tx = threadIdx.x & 31, ty = threadIdx.x >> 5;
    const int c = bxw * 32 + tx;
    const int rbase = byw * 32;
#pragma unroll
    for (int i = 0; i < 4; ++i)
        tle[ty + i * 8][tx] = W[(size_t)(rbase + ty + i * 8) * 1024 + c];
    __syncthreads();
    const int kT = byw * 32 + tx;
    const int nT = bxw * 32;
#pragma unroll
    for (int i = 0; i < 4; ++i)
        Wt[(size_t)(nT + ty + i * 8) * 1024 + kT] = f2bf(tle[tx][ty + i * 8]);
}

extern "C" void kernel_launch(void* const* d_in, const int* in_sizes, int n_in,
                              void* d_out, int out_size, void* d_ws, size_t ws_size,
                              hipStream_t stream)
{
    (void)in_sizes; (void)n_in; (void)out_size; (void)ws_size;

    const float* x  = (const float*)d_in[0];
    const float* Wq = (const float*)d_in[1];
    const float* Wk = (const float*)d_in[2];
    const float* Wv = (const float*)d_in[3];
    float* out = (float*)d_out;

    const int NB = 4, S = 2048, D = 1024;
    const long long SD  = (long long)S * D;     // 2,097,152
    const long long NSD = NB * SD;              // 8,388,608
    const long long SS  = (long long)S * S;     // 4,194,304

    // workspace (~150 MB): xb | Wt3 | QKVb | Vt | Sc
    ushort* xb   = (ushort*)d_ws;
    ushort* Wt3  = xb   + NSD;
    ushort* QKVb = Wt3  + 3 * (size_t)D * D;    // [8192][3072] bf16 (Q/K used)
    ushort* Vt   = QKVb + (size_t)NB * S * 3 * D;
    float*  Sc   = (float*)(Vt + NSD);          // NB*S*S fp32 (P overlays bf16)

    dim3 blk(256), blk5(512);

    // 1) conversions (merged launch)
    cvt_all<<<dim3(8192 + 3072), blk, 0, stream>>>(
        (const float4*)x, (ushort4*)xb, Wq, Wk, Wv, Wt3);

    // 2) merged QKV projection; V transposed in-epilogue; XCD-swizzled
    dim3 gp(3 * D / 256, (unsigned)(NB * S / 128), 1);
    gemm_bf16<128, 256, 0, 1><<<gp, blk5, 0, stream>>>(
        xb, Wt3, nullptr, QKVb, Vt,
        3 * D, D, D, D, 0, 0, 0, 1.f);

    // 3) scores = Q K^T / 32, 128x256 tiles, longest rows first
    dim3 gs(S / 256, S / 128, NB);
    gemm_bf16<128, 256, 1, 0><<<gs, blk5, 0, stream>>>(
        QKVb, QKVb + 1024, Sc, nullptr, nullptr,
        S, D, 3 * D, 3 * D, (long long)S * 3 * D, (long long)S * 3 * D,
        SS, 0.03125f);

    // 4) softmax fp32 -> bf16 P in place (read+write trimmed)
    softmax_bf16<<<dim3(S, NB), blk, 0, stream>>>(Sc);

    // 5) out = P V^T, 128x256 tiles, k-clipped, longest rows first
    dim3 gv(D / 256, S / 128, NB);
    gemm_bf16<128, 256, 2, 0><<<gv, blk5, 0, stream>>>(
        (const ushort*)Sc, Vt, out, nullptr, nullptr,
        D, S, 2 * S, S, 2 * SS, SD, SD, 1.f);
}